// Round 5
// baseline (1007.733 us; speedup 1.0000x reference)
//
#include <hip/hip_runtime.h>
#include <hip/hip_bf16.h>
#include <math.h>

#define N_ATOMS 50000
#define N_EDGES 1600000
#define FDIM 128
#define NB 25
#define CUTOFF_F 5.0f
#define PI_OVER_CUTOFF 0.6283185307179586f

typedef __bf16 bf16x8 __attribute__((ext_vector_type(8)));
typedef float f32x4 __attribute__((ext_vector_type(4)));

__device__ __forceinline__ float swish_f(float v) {
    return v / (1.0f + __expf(-v));
}

// XOR swizzle on 16B slots.
#define SWZ(row) ((((row) & 7) ^ (((row) >> 3) & 1)) << 4)

// ---------------- sort-by-dst machinery ----------------

__global__ void hist_kernel(const int* __restrict__ dst, int* __restrict__ count) {
    int i = blockIdx.x * 256 + threadIdx.x;
    if (i < N_EDGES) atomicAdd(&count[dst[i]], 1);
}

// Single block, 256 threads. No cross-lane intrinsics: per-thread chunk sums,
// thread-0 serial scan of the 256 partials, then per-thread cursor writes.
__global__ __launch_bounds__(256) void scan_simple_kernel(
    const int* __restrict__ count, int* __restrict__ cursor)
{
    __shared__ int ssum[256];
    const int t = threadIdx.x;
    const int CH = (N_ATOMS + 255) / 256;   // 196
    const int lo = t * CH;
    const int hi = (lo + CH < N_ATOMS) ? lo + CH : N_ATOMS;

    int s = 0;
    for (int b = lo; b < hi; ++b) s += count[b];
    ssum[t] = s;
    __syncthreads();

    if (t == 0) {
        int run = 0;
        for (int i = 0; i < 256; ++i) {
            int tmp = ssum[i];
            ssum[i] = run;
            run += tmp;
        }
    }
    __syncthreads();

    int run = ssum[t];
    for (int b = lo; b < hi; ++b) {
        cursor[b] = run;
        run += count[b];
    }
}

__global__ void scatter_kernel(const int* __restrict__ dst, int* __restrict__ cursor,
                               int* __restrict__ perm) {
    int i = blockIdx.x * 256 + threadIdx.x;
    if (i < N_EDGES) {
        int d = dst[i];
        int p = atomicAdd(&cursor[d], 1);
        perm[p] = i;
    }
}

// ---------------- weight packing ----------------

__global__ void pack_b_kernel(const float* __restrict__ W, __bf16* __restrict__ out,
                              int K_eff, int KS)
{
    int idx = blockIdx.x * 256 + threadIdx.x;
    int total = KS * 8 * 64 * 8;
    if (idx >= total) return;
    int j  = idx & 7;
    int l  = (idx >> 3) & 63;
    int n  = (idx >> 9) & 7;
    int ks = idx >> 12;
    int k   = ks * 32 + ((l >> 4) << 3) + j;
    int col = (n << 4) + (l & 15);
    float v = (k < K_eff) ? W[k * FDIM + col] : 0.0f;
    out[idx] = (__bf16)v;
}

// ---------------- node GEMM (fp32 compute) ----------------
// If out_bf != null: write bf16 (row-major, same layout). Else f32 to out_f32.

__global__ __launch_bounds__(256, 4) void node_gemm_kernel(
    const float* __restrict__ A, const float* __restrict__ W,
    const float* __restrict__ bias, float* __restrict__ out_f32,
    __bf16* __restrict__ out_bf, int n_rows, int do_swish)
{
    __shared__ float As[32 * 132];
    __shared__ float Ws[16 * 128];

    const int t = threadIdx.x;
    const int row0 = blockIdx.x * 32;
    const int c4 = (t & 31) * 4;
    const int rb = (t >> 5) * 4;

    for (int v = t; v < 1024; v += 256) {
        int r = v >> 5;
        int c = (v & 31) * 4;
        float4 val;
        if (row0 + r < n_rows) val = *(const float4*)&A[(size_t)(row0 + r) * FDIM + c];
        else val = make_float4(0.f, 0.f, 0.f, 0.f);
        *(float4*)&As[r * 132 + c] = val;
    }

    float acc[4][4];
    #pragma unroll
    for (int i = 0; i < 4; ++i)
        #pragma unroll
        for (int j = 0; j < 4; ++j) acc[i][j] = 0.f;

    for (int k0 = 0; k0 < 128; k0 += 16) {
        __syncthreads();
        for (int v = t; v < 512; v += 256)
            *(float4*)&Ws[v * 4] = *(const float4*)&W[k0 * 128 + v * 4];
        __syncthreads();
        #pragma unroll
        for (int kq = 0; kq < 4; ++kq) {
            const int kk = kq * 4;
            float4 w0 = *(float4*)&Ws[(kk + 0) * 128 + c4];
            float4 w1 = *(float4*)&Ws[(kk + 1) * 128 + c4];
            float4 w2 = *(float4*)&Ws[(kk + 2) * 128 + c4];
            float4 w3 = *(float4*)&Ws[(kk + 3) * 128 + c4];
            #pragma unroll
            for (int i = 0; i < 4; ++i) {
                float4 av = *(float4*)&As[(rb + i) * 132 + k0 + kk];
                acc[i][0] += av.x * w0.x + av.y * w1.x + av.z * w2.x + av.w * w3.x;
                acc[i][1] += av.x * w0.y + av.y * w1.y + av.z * w2.y + av.w * w3.y;
                acc[i][2] += av.x * w0.z + av.y * w1.z + av.z * w2.z + av.w * w3.z;
                acc[i][3] += av.x * w0.w + av.y * w1.w + av.z * w2.w + av.w * w3.w;
            }
        }
    }

    float4 bv = make_float4(0.f, 0.f, 0.f, 0.f);
    if (bias) bv = *(const float4*)&bias[c4];
    #pragma unroll
    for (int i = 0; i < 4; ++i) {
        int r = row0 + rb + i;
        if (r < n_rows) {
            float o[4];
            o[0] = acc[i][0] + bv.x;
            o[1] = acc[i][1] + bv.y;
            o[2] = acc[i][2] + bv.z;
            o[3] = acc[i][3] + bv.w;
            if (do_swish) {
                #pragma unroll
                for (int c = 0; c < 4; ++c) o[c] = swish_f(o[c]);
            }
            if (out_bf) {
                #pragma unroll
                for (int c = 0; c < 4; ++c)
                    out_bf[(size_t)r * FDIM + c4 + c] = (__bf16)o[c];
            } else {
                float4 ov = make_float4(o[0], o[1], o[2], o[3]);
                *(float4*)&out_f32[(size_t)r * FDIM + c4] = ov;
            }
        }
    }
}

// ---------------- MFMA edge kernel over dst-sorted perm ----------------
// Round-2 GEMM core; epilogue = direct global atomics with per-lane register
// run-compression over each lane's 4 consecutive (sorted) edges.

__global__ __launch_bounds__(256, 4) void edge_kernel(
    const float* __restrict__ fij, const float* __restrict__ rij,
    const int* __restrict__ src, const int* __restrict__ dst,
    const int* __restrict__ perm,
    const __bf16* __restrict__ w1p, const float* __restrict__ b1,
    const __bf16* __restrict__ w2p, const float* __restrict__ b2,
    const __bf16* __restrict__ xb, float* __restrict__ agg)
{
    __shared__ float fs[64 * 32];     // fij tile, swizzled
    __shared__ __bf16 hs[64 * 128];   // H tile, bf16, swizzled
    __shared__ int eidS[64], seS[64], deS[64];
    __shared__ float CeS[64];

    const int t = threadIdx.x;
    const int l = t & 63;
    const int w = t >> 6;
    const int e0 = blockIdx.x * 64;
    const int lrow = l & 15;
    const int kgrp = l >> 4;
    const int row = (w << 4) | lrow;

    if (t < 64) {
        int eid = perm[e0 + t];
        eidS[t] = eid;
        seS[t] = src[eid];
        deS[t] = dst[eid];
        float rr = rij[eid];
        CeS[t] = (rr < CUTOFF_F) ? 0.5f * (__cosf(rr * PI_OVER_CUTOFF) + 1.0f) : 0.0f;
    }
    __syncthreads();

    // gather fij rows -> fs (swizzled, K padded to 32)
    for (int idx = t; idx < 64 * 32; idx += 256) {
        int e = idx >> 5;
        int k = idx & 31;
        float v = (k < NB) ? fij[(size_t)eidS[e] * NB + k] : 0.0f;
        int byte = (e << 7) + (k << 2);
        byte ^= SWZ(e);
        *(float*)((char*)fs + byte) = v;
    }
    __syncthreads();

    const f32x4 zero = {0.f, 0.f, 0.f, 0.f};

    // GEMM1: H = swish(fij_pad @ W1 + b1) -> hs
    {
        int b0 = (row << 7) + (kgrp << 5);
        b0 ^= SWZ(row);
        float4 flo = *(const float4*)((const char*)fs + b0);
        float4 fhi = *(const float4*)((const char*)fs + (b0 ^ 16));
        bf16x8 a;
        a[0] = (__bf16)flo.x; a[1] = (__bf16)flo.y; a[2] = (__bf16)flo.z; a[3] = (__bf16)flo.w;
        a[4] = (__bf16)fhi.x; a[5] = (__bf16)fhi.y; a[6] = (__bf16)fhi.z; a[7] = (__bf16)fhi.w;

        #pragma unroll
        for (int n = 0; n < 8; ++n) {
            bf16x8 b = *(const bf16x8*)(w1p + (((n << 6) + l) << 3));
            f32x4 h = __builtin_amdgcn_mfma_f32_16x16x32_bf16(a, b, zero, 0, 0, 0);
            float bb = b1[(n << 4) + lrow];
            #pragma unroll
            for (int r = 0; r < 4; ++r) {
                int hrow = (w << 4) + (kgrp << 2) + r;
                float hv = swish_f(h[r] + bb);
                int byte = (hrow << 8) + (((n << 4) + lrow) << 1);
                byte ^= SWZ(hrow);
                *(__bf16*)((char*)hs + byte) = (__bf16)hv;
            }
        }
    }
    __syncthreads();

    // GEMM2: Wfilt = H @ W2
    f32x4 acc[8];
    #pragma unroll
    for (int n = 0; n < 8; ++n) acc[n] = zero;

    #pragma unroll
    for (int ks = 0; ks < 4; ++ks) {
        int byte = (row << 8) + (ks << 6) + (kgrp << 4);
        byte ^= SWZ(row);
        bf16x8 a = *(const bf16x8*)((const char*)hs + byte);
        #pragma unroll
        for (int n = 0; n < 8; ++n) {
            bf16x8 b = *(const bf16x8*)(w2p + ((((ks << 3) + n) << 6) + l) * 8);
            acc[n] = __builtin_amdgcn_mfma_f32_16x16x32_bf16(a, b, acc[n], 0, 0, 0);
        }
    }

    // Epilogue: m = x[src]*(Wfilt+b2)*C; run-compressed direct atomics.
    {
        const int els = (w << 4) + (kgrp << 2);   // this lane's 4 edges
        int se4[4], de4[4];
        float Cf[4];
        #pragma unroll
        for (int r = 0; r < 4; ++r) {
            se4[r] = seS[els + r];
            de4[r] = deS[els + r];
            Cf[r] = CeS[els + r];
        }
        const bool brk0 = (de4[0] != de4[1]);
        const bool brk1 = (de4[1] != de4[2]);
        const bool brk2 = (de4[2] != de4[3]);

        #pragma unroll
        for (int n = 0; n < 8; ++n) {
            int col = (n << 4) + lrow;
            float b2v = b2[col];
            float m[4];
            #pragma unroll
            for (int r = 0; r < 4; ++r) {
                float wf = acc[n][r] + b2v;
                m[r] = (float)xb[(size_t)se4[r] * FDIM + col] * wf * Cf[r];
            }
            // register run-compression (correct for any order of de4)
            float run = m[0];
            if (brk0) { unsafeAtomicAdd(&agg[(size_t)de4[0] * FDIM + col], run); run = 0.f; }
            run += m[1];
            if (brk1) { unsafeAtomicAdd(&agg[(size_t)de4[1] * FDIM + col], run); run = 0.f; }
            run += m[2];
            if (brk2) { unsafeAtomicAdd(&agg[(size_t)de4[2] * FDIM + col], run); run = 0.f; }
            run += m[3];
            unsafeAtomicAdd(&agg[(size_t)de4[3] * FDIM + col], run);
        }
    }
}

extern "C" void kernel_launch(void* const* d_in, const int* in_sizes, int n_in,
                              void* d_out, int out_size, void* d_ws, size_t ws_size,
                              hipStream_t stream)
{
    const float* feat   = (const float*)d_in[0];
    const float* fij    = (const float*)d_in[1];
    const float* rij    = (const float*)d_in[2];
    const int*   src    = (const int*)d_in[3];
    const int*   dst    = (const int*)d_in[4];
    const float* W_in2f = (const float*)d_in[5];
    const float* W_f1   = (const float*)d_in[6];
    const float* b_f1   = (const float*)d_in[7];
    const float* W_f2   = (const float*)d_in[8];
    const float* b_f2   = (const float*)d_in[9];
    const float* W_out  = (const float*)d_in[10];
    const float* b_out  = (const float*)d_in[11];
    float* out = (float*)d_out;

    // ws layout, total 19,640,960 B (< round-2-proven 25.67 MB watermark)
    char* ws = (char*)d_ws;
    __bf16* xb     = (__bf16*)ws;                     // 12,800,000 B
    __bf16* w1p    = (__bf16*)(ws + 12800000);        //      8,192 B
    __bf16* w2p    = (__bf16*)(ws + 12808192);        //     32,768 B
    int*    cursor = (int*)(ws + 12840960);           //    200,000 B
    int*    count  = (int*)(ws + 13040960);           //    200,000 B
    int*    perm   = (int*)(ws + 13240960);           //  6,400,000 B
    float*  agg    = out;                             // accumulate into d_out

    hipMemsetAsync(agg, 0, (size_t)N_ATOMS * FDIM * sizeof(float), stream);
    hipMemsetAsync(count, 0, N_ATOMS * sizeof(int), stream);

    hist_kernel<<<(N_EDGES + 255) / 256, 256, 0, stream>>>(dst, count);
    scan_simple_kernel<<<1, 256, 0, stream>>>(count, cursor);
    scatter_kernel<<<(N_EDGES + 255) / 256, 256, 0, stream>>>(dst, cursor, perm);

    pack_b_kernel<<<(4096 + 255) / 256, 256, 0, stream>>>(W_f1, w1p, NB, 1);
    pack_b_kernel<<<(16384 + 255) / 256, 256, 0, stream>>>(W_f2, w2p, 128, 4);

    node_gemm_kernel<<<(N_ATOMS + 31) / 32, 256, 0, stream>>>(
        feat, W_in2f, nullptr, nullptr, xb, N_ATOMS, 0);

    edge_kernel<<<N_EDGES / 64, 256, 0, stream>>>(
        fij, rij, src, dst, perm, w1p, b_f1, w2p, b_f2, xb, agg);

    node_gemm_kernel<<<(N_ATOMS + 31) / 32, 256, 0, stream>>>(
        agg, W_out, b_out, out, nullptr, N_ATOMS, 1);
}